// Round 9
// baseline (371.502 us; speedup 1.0000x reference)
//
#include <hip/hip_runtime.h>
#include <stdint.h>

#define T_ 128

typedef int v4i __attribute__((ext_vector_type(4)));

// ---------------------------------------------------------------------------
// prep 1: static B-fragments for mfma_i32_16x16x64_i8, biased i8 (byte-128).
// Fragment mf = (tau*5 + kappa)*2 + h. Lane l holds n = l&15,
// k-slots kin = (l>>4)*16 + 4r + b — identical slot->k map as scan's A, so
// any HW k-permutation cancels in the dot.
__global__ void prep_bfrag(const int* __restrict__ sc, uint4* __restrict__ bf) {
  int gid = blockIdx.x * 256 + threadIdx.x;
  if (gid >= 160 * 64) return;
  int mf = gid >> 6, l = gid & 63;
  int tau = mf / 10, rem = mf % 10;
  int kap = rem >> 1, h = rem & 1;
  int j = 16 * tau + (l & 15);
  int kinb = (l >> 4) * 16;
  unsigned wout[4];
#pragma unroll
  for (int r = 0; r < 4; ++r) {
    unsigned wrd = 0;
#pragma unroll
    for (int be = 0; be < 4; ++be) {
      int kin = kinb + 4 * r + be;
      int col = (kap == 0) ? kin : 64 + ((kap - 1) << 6) + kin;
      unsigned c = (unsigned)sc[j * 320 + col];
      unsigned byte = (h ? (c >> 8) : c) & 0xFFu;
      byte = (byte - 128u) & 0xFFu;
      wrd |= byte << (8 * be);
    }
    wout[r] = wrd;
  }
  bf[gid] = make_uint4(wout[0], wout[1], wout[2], wout[3]);
}

// prep 2: window bits packed to u64 per (b,t)
__global__ void prep_wbits(const int* __restrict__ bits,
                           unsigned long long* __restrict__ wb) {
  int gid = blockIdx.x * 256 + threadIdx.x;
  int wv = gid >> 6, lane = gid & 63;
  unsigned long long m = __ballot(bits[gid] != 0);
  if (lane == 0) wb[wv] = m;
}

// prep 3: bitpack (state_mem >= 0.5) -> 2 MiB table (L2-resident for scan)
__global__ void prep_bitpack(const float* __restrict__ sm,
                             unsigned long long* __restrict__ packed) {
  int base = blockIdx.x * (256 * 32) + threadIdx.x;
  int lane = threadIdx.x & 63;
#pragma unroll 1
  for (int it = 0; it < 32; ++it) {
    int idx = base + it * 256;
    float v = sm[idx];
    unsigned long long m = __ballot(v >= 0.5f);
    if (lane == 0) packed[idx >> 6] = m;
  }
}

// ---------------------------------------------------------------------------
// per-lane expand of a 16-bit slice into an i8 {0,1} A-fragment (window only)
static __device__ __forceinline__ v4i expand16(unsigned b16) {
  v4i a;
#pragma unroll
  for (int r = 0; r < 4; ++r) {
    unsigned nib = (b16 >> (4 * r)) & 0xFu;
    a[r] = (int)((nib * 0x00204081u) & 0x01010101u);
  }
  return a;
}

// ---------------------------------------------------------------------------
// scan + heads, R9 (= R8 with the sync-counter bug fixed): TWO decoupled
// 4-wave scan groups per block (rows 2*blk, 2*blk+1), 64 blocks x 512
// threads. Wave i and i+4 share a SIMD -> each SIMD carries one wave of
// EACH group; groups sync on their own LDS counter instead of the
// block-wide s_barrier, so when one group stalls in gather/exchange the
// other group's MFMAs fill the matrix pipe.
//
// R8 BUG: the release-add executed PER LANE (+64/wave/step; the compiler
// coalesces to a single +active-lane-count add — still 64), so the spin
// target 4*(t+1) was passed before any other wave published -> race.
// FIX: lane 0 only adds (+1/wave/step). Release on lane 0's ds_add is
// wave-wide (waitcnt lgkmcnt(0) drains all 64 lanes' byte-stores first),
// acquire on the spin load orders the subsequent ds_reads.
//
// Race-freedom (re-audited): within a wave, reads of buf[cur] precede the
// write+add of buf[nxt]; a wave passes spin(4(t+1)) only after ALL group
// waves added for step t, hence after their reads of buf[t&1] completed;
// a wave at step t+2 overwrites buf[(t+1)&1] only after passing sync(t+1),
// which postdates every group wave's reads at t+1 -> 2-buffer ping-pong
// safe with ONE sync per step, max skew 1 step.
__global__ __launch_bounds__(512, 2) void scan_heads(
    const uint4* __restrict__ bfrag,
    const unsigned* __restrict__ packed32,
    const unsigned long long* __restrict__ wbits,
    const int* __restrict__ head_conn,
    const int* __restrict__ head_coeffs,
    const float* __restrict__ head_mem,
    float* __restrict__ out) {
  __shared__ __align__(16) unsigned char ab[2][2][256];  // [grp][buf][state]
  __shared__ __align__(16) unsigned mcnt[2][2][4];       // [grp][buf][wave]
  __shared__ unsigned ctr[2];                            // per-group sync ctr
  const int tid = threadIdx.x;
  const int w = tid >> 6, l = tid & 63;
  const int g = w >> 2, wg = w & 3;     // group, wave-in-group
  const int qq = l >> 4;
  const int j = 64 * wg + l;            // this lane's state within the group
  const int row = 2 * blockIdx.x + g;   // batch row this group scans

  // one-time: 40 static B-fragments (tiles 4wg..4wg+3, kappa 0..4)
  v4i bf[4][5][2];
#pragma unroll
  for (int i = 0; i < 4; ++i)
#pragma unroll
    for (int k = 0; k < 5; ++k)
#pragma unroll
      for (int h = 0; h < 2; ++h) {
        int mf = ((4 * wg + i) * 5 + k) * 2 + h;
        bf[i][k][h] = __builtin_bit_cast(v4i, bfrag[mf * 64 + l]);
      }

  // init: state0 = 0, counters 0 (tid&255 spans each group's 256 slots)
  ab[g][0][tid & 255] = (unsigned char)0;
  if ((tid & 255) < 4) mcnt[g][0][tid & 255] = 0u;
  if ((tid & 255) == 0) ctr[g] = 0u;

  const unsigned* pkrow = packed32 + ((size_t)j << 11);
  unsigned long long wcur = wbits[row * 128];

  // prologue: t=0 window term + bias term
  v4i wacc[4][2];
  unsigned wcorr;
  {
    v4i aw = expand16((unsigned)((wcur >> (16 * qq)) & 0xFFFFu));
    v4i z = (v4i){0, 0, 0, 0};
#pragma unroll
    for (int i = 0; i < 4; ++i)
#pragma unroll
      for (int h = 0; h < 2; ++h)
        wacc[i][h] = __builtin_amdgcn_mfma_i32_16x16x64_i8(aw, bf[i][0][h], z, 0, 0, 0);
    wcorr = (unsigned)__popcll(wcur) * 32896u;
  }
  __syncthreads();  // one block-wide sync to cover LDS init; groups decouple after

#pragma unroll 2
  for (int t = 0; t < T_; ++t) {
    const int cur = t & 1, nxt = cur ^ 1;

    // prefetch next step's window row (independent, issued early)
    int tn = (t + 1 < T_) ? t + 1 : t;
    unsigned long long wnext = wbits[row * 128 + tn];

    // LDS reads first: 4 broadcast A-frags + popcount fixups
    const unsigned char* abase = &ab[g][cur][16 * qq];
    v4i a0 = *(const v4i*)(abase);
    v4i a1 = *(const v4i*)(abase + 64);
    v4i a2 = *(const v4i*)(abase + 128);
    v4i a3 = *(const v4i*)(abase + 192);
    uint4 cz = *((const uint4*)&mcnt[g][cur][0]);

    // 32 state MFMAs, four independent 1-deep chains per (tile,h).
    // accP seeded by the window contribution (computed last iteration).
    v4i z = (v4i){0, 0, 0, 0};
    v4i accP[4][2], accQ[4][2], accR[4][2], accS[4][2];
#pragma unroll
    for (int i = 0; i < 4; ++i) {
      accP[i][0] = __builtin_amdgcn_mfma_i32_16x16x64_i8(a0, bf[i][1][0], wacc[i][0], 0, 0, 0);
      accP[i][1] = __builtin_amdgcn_mfma_i32_16x16x64_i8(a0, bf[i][1][1], wacc[i][1], 0, 0, 0);
      accQ[i][0] = __builtin_amdgcn_mfma_i32_16x16x64_i8(a1, bf[i][2][0], z, 0, 0, 0);
      accQ[i][1] = __builtin_amdgcn_mfma_i32_16x16x64_i8(a1, bf[i][2][1], z, 0, 0, 0);
      accR[i][0] = __builtin_amdgcn_mfma_i32_16x16x64_i8(a2, bf[i][3][0], z, 0, 0, 0);
      accR[i][1] = __builtin_amdgcn_mfma_i32_16x16x64_i8(a2, bf[i][3][1], z, 0, 0, 0);
      accS[i][0] = __builtin_amdgcn_mfma_i32_16x16x64_i8(a3, bf[i][4][0], z, 0, 0, 0);
      accS[i][1] = __builtin_amdgcn_mfma_i32_16x16x64_i8(a3, bf[i][4][1], z, 0, 0, 0);
    }

    // epilogue: lane l owns state j = 64wg+l -> tile i = l>>4, col l&15, reg 0
    unsigned csum = cz.x + cz.y + cz.z + cz.w + wcorr;
    unsigned tv0 = ((unsigned)accP[0][0][0] + (unsigned)accQ[0][0][0] +
                    (unsigned)accR[0][0][0] + (unsigned)accS[0][0][0]) +
                   (((unsigned)accP[0][1][0] + (unsigned)accQ[0][1][0] +
                     (unsigned)accR[0][1][0] + (unsigned)accS[0][1][0]) << 8);
    unsigned tv1 = ((unsigned)accP[1][0][0] + (unsigned)accQ[1][0][0] +
                    (unsigned)accR[1][0][0] + (unsigned)accS[1][0][0]) +
                   (((unsigned)accP[1][1][0] + (unsigned)accQ[1][1][0] +
                     (unsigned)accR[1][1][0] + (unsigned)accS[1][1][0]) << 8);
    unsigned tv2 = ((unsigned)accP[2][0][0] + (unsigned)accQ[2][0][0] +
                    (unsigned)accR[2][0][0] + (unsigned)accS[2][0][0]) +
                   (((unsigned)accP[2][1][0] + (unsigned)accQ[2][1][0] +
                     (unsigned)accR[2][1][0] + (unsigned)accS[2][1][0]) << 8);
    unsigned tv3 = ((unsigned)accP[3][0][0] + (unsigned)accQ[3][0][0] +
                    (unsigned)accR[3][0][0] + (unsigned)accS[3][0][0]) +
                   (((unsigned)accP[3][1][0] + (unsigned)accQ[3][1][0] +
                     (unsigned)accR[3][1][0] + (unsigned)accS[3][1][0]) << 8);
    unsigned t01 = (l & 16) ? tv1 : tv0;
    unsigned t23 = (l & 16) ? tv3 : tv2;
    unsigned ad = (((l & 32) ? t23 : t01) + csum) & 0xFFFFu;

    // self-gather: one bit per lane, 256 per group (L2-resident table)
    unsigned word = pkrow[ad >> 5];

    // fill the gather latency shadow: next step's window MFMAs + bias term
    {
      v4i aw = expand16((unsigned)((wnext >> (16 * qq)) & 0xFFFFu));
#pragma unroll
      for (int i = 0; i < 4; ++i)
#pragma unroll
        for (int h = 0; h < 2; ++h)
          wacc[i][h] = __builtin_amdgcn_mfma_i32_16x16x64_i8(aw, bf[i][0][h], z, 0, 0, 0);
      wcorr = (unsigned)__popcll(wnext) * 32896u;
    }

    unsigned bitv = (word >> (ad & 31)) & 1u;
    unsigned long long mq = __ballot(bitv != 0u);
    ab[g][nxt][j] = (unsigned char)bitv;
    if (l == 0) mcnt[g][nxt][wg] = (unsigned)__popcll(mq) * 32896u;

    // decoupled group sync. LANE 0 ONLY adds (+1/wave/step — R8's bug was
    // per-lane adds, +64). Release drains this wave's LDS byte-stores
    // (wave-wide lgkmcnt) before the add; acquire-spin orders the next
    // step's ds_reads after all 4 group waves have published.
    if (l == 0)
      __hip_atomic_fetch_add(&ctr[g], 1u, __ATOMIC_RELEASE,
                             __HIP_MEMORY_SCOPE_WORKGROUP);
    const unsigned tgt = 4u * (unsigned)(t + 1);
    while (__hip_atomic_load(&ctr[g], __ATOMIC_ACQUIRE,
                             __HIP_MEMORY_SCOPE_WORKGROUP) < tgt) {
    }
    __builtin_amdgcn_sched_barrier(0);

    wcur = wnext;
  }

  // ---- heads (group leader wave): only the selected head per batch row
  if (wg == 0) {
    // wcur == window row t=127 (tn clamps at the last step)
    int h = (int)((((wcur >> 61) & 1) << 2) | (((wcur >> 62) & 1) << 1) |
                  ((wcur >> 63) & 1));
    int ho = h * 64 + l;
    const int4* cn4 = (const int4*)(head_conn + ho * 8);
    const int4* cf4 = (const int4*)(head_coeffs + ho * 8);
    int4 cna = cn4[0], cnb = cn4[1];
    int4 cfa = cf4[0], cfb = cf4[1];
    int cns[8] = {cna.x, cna.y, cna.z, cna.w, cnb.x, cnb.y, cnb.z, cnb.w};
    int cfs[8] = {cfa.x, cfa.y, cfa.z, cfa.w, cfb.x, cfb.y, cfb.z, cfb.w};
    unsigned addr = 0;
#pragma unroll
    for (int k = 0; k < 8; ++k) {
      addr += (unsigned)ab[g][T_ & 1][cns[k]] * (unsigned)cfs[k];
    }
    addr &= 0xFFFFu;
    out[row * 64 + l] = head_mem[((size_t)ho << 16) + addr];
  }
}

extern "C" void kernel_launch(void* const* d_in, const int* in_sizes, int n_in,
                              void* d_out, int out_size, void* d_ws, size_t ws_size,
                              hipStream_t stream) {
  const int*   bits         = (const int*)d_in[0];
  const int*   state_coeffs = (const int*)d_in[1];
  const float* state_mem    = (const float*)d_in[2];
  const int*   head_conn    = (const int*)d_in[3];
  const int*   head_coeffs  = (const int*)d_in[4];
  const float* head_mem     = (const float*)d_in[5];
  float* out = (float*)d_out;

  char* ws = (char*)d_ws;
  uint4*              bfrag  = (uint4*)ws;                              // 160 KiB
  unsigned long long* wbits  = (unsigned long long*)(ws + (160 << 10)); // 128 KiB
  unsigned*           packed = (unsigned*)(ws + (288 << 10));           // 2 MiB

  prep_bfrag<<<40, 256, 0, stream>>>(state_coeffs, bfrag);
  prep_wbits<<<4096, 256, 0, stream>>>(bits, wbits);
  prep_bitpack<<<2048, 256, 0, stream>>>(state_mem, (unsigned long long*)packed);
  scan_heads<<<64, 512, 0, stream>>>(bfrag, packed, wbits,
                                     head_conn, head_coeffs, head_mem, out);
}

// Round 10
// 308.315 us; speedup vs baseline: 1.2049x; 1.2049x over previous
//
#include <hip/hip_runtime.h>
#include <stdint.h>

#define T_ 128

typedef int v4i __attribute__((ext_vector_type(4)));

// ---------------------------------------------------------------------------
// fused prep: three independent preps in ONE launch (disjoint block ranges)
// so they run concurrently instead of serializing on the stream.
//   blocks [0,40):        B-fragments for mfma_i32_16x16x64_i8 (biased i8).
//   blocks [40,4136):     window bits packed to u64 per (b,t).
//   blocks [4136,6184):   bitpack (state_mem >= 0.5) -> 2 MiB table.
// B-fragment layout: mf = (tau*5+kappa)*2+h; lane l holds n=l&15, k-slots
// kin = (l>>4)*16+4r+b — identical slot->k map as scan's A, so any HW
// k-permutation cancels in the dot.
__global__ void prep_all(const int* __restrict__ sc,
                         const int* __restrict__ bits,
                         const float* __restrict__ sm,
                         uint4* __restrict__ bf,
                         unsigned long long* __restrict__ wb,
                         unsigned long long* __restrict__ packed) {
  const int blk = blockIdx.x;
  if (blk < 40) {
    // ---- prep_bfrag
    int gid = blk * 256 + threadIdx.x;   // [0, 10240) = 160*64 exactly
    int mf = gid >> 6, l = gid & 63;
    int tau = mf / 10, rem = mf % 10;
    int kap = rem >> 1, h = rem & 1;
    int j = 16 * tau + (l & 15);
    int kinb = (l >> 4) * 16;
    unsigned wout[4];
#pragma unroll
    for (int r = 0; r < 4; ++r) {
      unsigned wrd = 0;
#pragma unroll
      for (int be = 0; be < 4; ++be) {
        int kin = kinb + 4 * r + be;
        int col = (kap == 0) ? kin : 64 + ((kap - 1) << 6) + kin;
        unsigned c = (unsigned)sc[j * 320 + col];
        unsigned byte = (h ? (c >> 8) : c) & 0xFFu;
        byte = (byte - 128u) & 0xFFu;
        wrd |= byte << (8 * be);
      }
      wout[r] = wrd;
    }
    bf[gid] = make_uint4(wout[0], wout[1], wout[2], wout[3]);
  } else if (blk < 40 + 4096) {
    // ---- prep_wbits
    int gid = (blk - 40) * 256 + threadIdx.x;
    int wv = gid >> 6, lane = gid & 63;
    unsigned long long m = __ballot(bits[gid] != 0);
    if (lane == 0) wb[wv] = m;
  } else {
    // ---- prep_bitpack
    int base = (blk - (40 + 4096)) * (256 * 32) + threadIdx.x;
    int lane = threadIdx.x & 63;
#pragma unroll 1
    for (int it = 0; it < 32; ++it) {
      int idx = base + it * 256;
      float v = sm[idx];
      unsigned long long m = __ballot(v >= 0.5f);
      if (lane == 0) packed[idx >> 6] = m;
    }
  }
}

// ---------------------------------------------------------------------------
// per-lane expand of a 16-bit slice into an i8 {0,1} A-fragment (window only)
static __device__ __forceinline__ v4i expand16(unsigned b16) {
  v4i a;
#pragma unroll
  for (int r = 0; r < 4; ++r) {
    unsigned nib = (b16 >> (4 * r)) & 0xFu;
    a[r] = (int)((nib * 0x00204081u) & 0x01010101u);
  }
  return a;
}

// ---------------------------------------------------------------------------
// scan + heads: byte-exact R7 structure (best measured: 96.0 us scan).
// 1 block per batch row, 8 waves of 64 (2 lean waves/SIMD). Wave w owns
// tiles {2w,2w+1} = states [32w,32w+32). Per step: ds_read A-frags from the
// byte table -> 16 state MFMAs (4 in-place depth-4 chains seeded by the
// window term computed last step in the gather shadow) -> short epilogue ->
// L2 self-gather (1 bit/lane, lanes<32) -> window MFMAs for t+1 in the
// gather latency shadow -> byte write -> raw lgkm-only s_barrier.
// R8/R9 lesson: s_barrier (wave-park) beats any LDS spin sync; R6 heater
// showed the SIMD is issue-contention-sensitive, so no extra streams.
__global__ __launch_bounds__(512, 2) void scan_heads(
    const uint4* __restrict__ bfrag,
    const unsigned* __restrict__ packed32,
    const unsigned long long* __restrict__ wbits,
    const int* __restrict__ head_conn,
    const int* __restrict__ head_coeffs,
    const float* __restrict__ head_mem,
    float* __restrict__ out) {
  __shared__ __align__(16) unsigned char ab[2][256];   // state bits as i8 bytes
  __shared__ __align__(16) unsigned mcnt[2][8];        // per-wave popcnt*32896
  const int tid = threadIdx.x;
  const int b = blockIdx.x;
  const int w = tid >> 6, l = tid & 63;
  const int qq = l >> 4;
  const int jg = 32 * w + (l & 31);     // this lane's state (lanes 0..31 live)

  // one-time: 20 static B-fragments (tiles 2w, 2w+1; kappa 0..4)
  v4i bf[2][5][2];
#pragma unroll
  for (int i = 0; i < 2; ++i)
#pragma unroll
    for (int k = 0; k < 5; ++k)
#pragma unroll
      for (int h = 0; h < 2; ++h) {
        int mf = ((2 * w + i) * 5 + k) * 2 + h;
        bf[i][k][h] = __builtin_bit_cast(v4i, bfrag[mf * 64 + l]);
      }

  if (tid < 256) ab[0][tid] = (unsigned char)0;   // state0 = 0
  if (tid < 8) mcnt[0][tid] = 0u;

  const unsigned* pkrow = packed32 + ((size_t)jg << 11);
  unsigned long long wcur = wbits[b * 128];

  // prologue: t=0 window term + bias term
  v4i wacc[2][2];
  unsigned wcorr;
  {
    v4i aw = expand16((unsigned)((wcur >> (16 * qq)) & 0xFFFFu));
    v4i z = (v4i){0, 0, 0, 0};
#pragma unroll
    for (int i = 0; i < 2; ++i)
#pragma unroll
      for (int h = 0; h < 2; ++h)
        wacc[i][h] = __builtin_amdgcn_mfma_i32_16x16x64_i8(aw, bf[i][0][h], z, 0, 0, 0);
    wcorr = (unsigned)__popcll(wcur) * 32896u;
  }
  __syncthreads();

#pragma unroll 2
  for (int t = 0; t < T_; ++t) {
    const int cur = t & 1, nxt = cur ^ 1;

    // prefetch next step's window row (independent, issued early)
    int tn = (t + 1 < T_) ? t + 1 : t;
    unsigned long long wnext = wbits[b * 128 + tn];

    // LDS reads first: 4 broadcast A-frags + popcount fixups
    const unsigned char* abase = &ab[cur][16 * qq];
    v4i a0 = *(const v4i*)(abase);
    v4i a1 = *(const v4i*)(abase + 64);
    v4i a2 = *(const v4i*)(abase + 128);
    v4i a3 = *(const v4i*)(abase + 192);
    uint4 c0 = *((const uint4*)&mcnt[cur][0]);
    uint4 c1 = *((const uint4*)&mcnt[cur][4]);

    // 16 state MFMAs: 4 in-place depth-4 chains (2 tiles x 2 h), window-seeded.
    // 8 chains per SIMD (2 waves) keep the pipe fed despite the dependences.
    v4i acc[2][2];
#pragma unroll
    for (int i = 0; i < 2; ++i)
#pragma unroll
      for (int h = 0; h < 2; ++h)
        acc[i][h] = __builtin_amdgcn_mfma_i32_16x16x64_i8(a0, bf[i][1][h], wacc[i][h], 0, 0, 0);
#pragma unroll
    for (int i = 0; i < 2; ++i)
#pragma unroll
      for (int h = 0; h < 2; ++h)
        acc[i][h] = __builtin_amdgcn_mfma_i32_16x16x64_i8(a1, bf[i][2][h], acc[i][h], 0, 0, 0);
#pragma unroll
    for (int i = 0; i < 2; ++i)
#pragma unroll
      for (int h = 0; h < 2; ++h)
        acc[i][h] = __builtin_amdgcn_mfma_i32_16x16x64_i8(a2, bf[i][3][h], acc[i][h], 0, 0, 0);
#pragma unroll
    for (int i = 0; i < 2; ++i)
#pragma unroll
      for (int h = 0; h < 2; ++h)
        acc[i][h] = __builtin_amdgcn_mfma_i32_16x16x64_i8(a3, bf[i][4][h], acc[i][h], 0, 0, 0);

    // epilogue: lane l (<32) owns state jg = 32w+(l&31); tile = (l>>4)&1
    unsigned csum = c0.x + c0.y + c0.z + c0.w + c1.x + c1.y + c1.z + c1.w + wcorr;
    unsigned tv0 = (unsigned)acc[0][0][0] + ((unsigned)acc[0][1][0] << 8);
    unsigned tv1 = (unsigned)acc[1][0][0] + ((unsigned)acc[1][1][0] << 8);
    unsigned ad = (((l & 16) ? tv1 : tv0) + csum) & 0xFFFFu;

    // self-gather: one bit per lane (lanes 0..31), 256 per block
    unsigned word = 0;
    if (l < 32) word = pkrow[ad >> 5];

    // fill the gather latency shadow: next step's window MFMAs + bias term
    {
      v4i aw = expand16((unsigned)((wnext >> (16 * qq)) & 0xFFFFu));
      v4i z = (v4i){0, 0, 0, 0};
#pragma unroll
      for (int i = 0; i < 2; ++i)
#pragma unroll
        for (int h = 0; h < 2; ++h)
          wacc[i][h] = __builtin_amdgcn_mfma_i32_16x16x64_i8(aw, bf[i][0][h], z, 0, 0, 0);
      wcorr = (unsigned)__popcll(wnext) * 32896u;
    }

    unsigned bitv = (word >> (ad & 31)) & 1u;
    unsigned long long mq = __ballot(l < 32 && bitv != 0u);
    if (l < 32) ab[nxt][jg] = (unsigned char)bitv;
    if (l == 0) mcnt[nxt][w] = (unsigned)__popc((unsigned)mq) * 32896u;

    // raw barrier: drain LDS only; global prefetches stay in flight
    asm volatile("s_waitcnt lgkmcnt(0)" ::: "memory");
    __builtin_amdgcn_sched_barrier(0);
    __builtin_amdgcn_s_barrier();
    __builtin_amdgcn_sched_barrier(0);

    wcur = wnext;
  }

  // ---- heads (wave 0): only the selected head per batch row
  if (w == 0) {
    // wcur == window row t=127 (tn clamps at the last step)
    int h = (int)((((wcur >> 61) & 1) << 2) | (((wcur >> 62) & 1) << 1) |
                  ((wcur >> 63) & 1));
    int ho = h * 64 + l;
    const int4* cn4 = (const int4*)(head_conn + ho * 8);
    const int4* cf4 = (const int4*)(head_coeffs + ho * 8);
    int4 cna = cn4[0], cnb = cn4[1];
    int4 cfa = cf4[0], cfb = cf4[1];
    int cns[8] = {cna.x, cna.y, cna.z, cna.w, cnb.x, cnb.y, cnb.z, cnb.w};
    int cfs[8] = {cfa.x, cfa.y, cfa.z, cfa.w, cfb.x, cfb.y, cfb.z, cfb.w};
    unsigned addr = 0;
#pragma unroll
    for (int k = 0; k < 8; ++k) {
      addr += (unsigned)ab[T_ & 1][cns[k]] * (unsigned)cfs[k];
    }
    addr &= 0xFFFFu;
    out[b * 64 + l] = head_mem[((size_t)ho << 16) + addr];
  }
}

extern "C" void kernel_launch(void* const* d_in, const int* in_sizes, int n_in,
                              void* d_out, int out_size, void* d_ws, size_t ws_size,
                              hipStream_t stream) {
  const int*   bits         = (const int*)d_in[0];
  const int*   state_coeffs = (const int*)d_in[1];
  const float* state_mem    = (const float*)d_in[2];
  const int*   head_conn    = (const int*)d_in[3];
  const int*   head_coeffs  = (const int*)d_in[4];
  const float* head_mem     = (const float*)d_in[5];
  float* out = (float*)d_out;

  char* ws = (char*)d_ws;
  uint4*              bfrag  = (uint4*)ws;                              // 160 KiB
  unsigned long long* wbits  = (unsigned long long*)(ws + (160 << 10)); // 128 KiB
  unsigned*           packed = (unsigned*)(ws + (288 << 10));           // 2 MiB

  prep_all<<<40 + 4096 + 2048, 256, 0, stream>>>(
      state_coeffs, bits, state_mem,
      bfrag, wbits, (unsigned long long*)packed);
  scan_heads<<<128, 512, 0, stream>>>(bfrag, packed, wbits,
                                      head_conn, head_coeffs, head_mem, out);
}